// Round 1
// baseline (279.722 us; speedup 1.0000x reference)
//
#include <hip/hip_runtime.h>

// SSIM loss, round 8: round-7 structure + LDS shrink for 6 blocks/CU +
// per-slot square hoisting in phase 2 + fused H reads in phase 3.
// imgs: (32, 3, 512, 512) fp32. Output: scalar 1 - mean(ssim_map).
//
// Per block: 32x32 output tile, fp32 throughout.
//  phase 1: stage 42x48 (x1,x2)-interleaved v2f tile (float4 global loads).
//  phase 2: 672 tasks = 42 rows x 16 col-PAIRS. Each task: 7 ds_read_b128
//           (14 v2f slots). NEW: loop per SLOT k=1..12, computing p*p and
//           p.x*p.y ONCE per slot and feeding both columns' accumulators
//           (old per-tap form computed squares of slots 2..11 twice:
//           176 -> 146 VALU ops/task).
//  barrier; H arrays OVERLAY the staging region. NEW layout: h0123 as
//           interleaved v4f[42][32] (mu-pair + sq-pair) + h4 f32[42][32]
//           = 26,880 B union (was 28,560 with stride-34 pads) ->
//           6 blocks/CU fit (6*26880 = 161,280 <= 163,840).
//  phase 3: vertical blur, 4 consecutive rows/thread; per dy now ONE
//           ds_read_b128 (h0123) + one b32 (h4) instead of 2xb64 + b32.
//           SSIM with v_rcp_f32, wave reduce, spread atomics.

#define HH 512
#define WW 512
#define TILE 32
#define IN_ROWS 42
#define S_STRIDE 50         // v2f stride of s12 (even -> b128 alignment holds)
#define H_STRIDE 32         // v4f/f32 stride of H arrays (tight, no pad)
#define NPLANES 96
#define NPIX 25165824.0f
#define NACC 256
#define NTASK 672           // 42 rows * 16 col-pairs

// union layout (bytes)
#define H0123_OFF 0                  // v4f [42][32] = 21504
#define H4_OFF  21504                // f32 [42][32] = 5376
#define UNION_BYTES 26880            // >= s12: v2f[42][50] = 16800

typedef float v2f __attribute__((ext_vector_type(2)));
typedef float v4f __attribute__((ext_vector_type(4)));

__global__ __launch_bounds__(256, 6) void ssim_fused_kernel(
    const float* __restrict__ img1, const float* __restrict__ img2,
    float* __restrict__ acc) {
  __shared__ __align__(16) char ub[UNION_BYTES];
  __shared__ float wsum[4];

  v2f (*s12)[S_STRIDE] = (v2f (*)[S_STRIDE])ub;
  v4f (*h0123)[H_STRIDE] = (v4f (*)[H_STRIDE])(ub + H0123_OFF);
  float (*h4)[H_STRIDE] = (float (*)[H_STRIDE])(ub + H4_OFF);

  const int tid = threadIdx.x;
  const int tx = blockIdx.x * TILE;
  const int ty = blockIdx.y * TILE;
  const size_t base = (size_t)blockIdx.z * (HH * WW);

  const float g[11] = {
      1.0283800e-03f, 7.5987600e-03f, 3.6000770e-02f, 1.0936072e-01f,
      2.1300560e-01f, 2.6601170e-01f, 2.1300560e-01f, 1.0936072e-01f,
      3.6000770e-02f, 7.5987600e-03f, 1.0283800e-03f};

  // ---- phase 1: float4 staging, interleave (x1,x2) into s12 ----
  // pixel slot = gx - (tx-8); 42 rows x 12 quads; quads 16B-aligned in global.
#pragma unroll
  for (int it = 0; it < 2; ++it) {
    int idx = it * 256 + tid;
    if (idx < IN_ROWS * 12) {
      int r = idx / 12;
      int p = idx - r * 12;
      int gy = ty - 5 + r;
      int gx = tx - 8 + 4 * p;
      v4f A = {0.f, 0.f, 0.f, 0.f}, B = {0.f, 0.f, 0.f, 0.f};
      if ((unsigned)gy < (unsigned)HH && (unsigned)gx < (unsigned)WW) {
        size_t off = base + (size_t)gy * WW + gx;
        A = *(const v4f*)(img1 + off);
        B = *(const v4f*)(img2 + off);
      }
      *(v4f*)&s12[r][4 * p]     = (v4f){A.x, B.x, A.y, B.y};
      *(v4f*)&s12[r][4 * p + 2] = (v4f){A.z, B.z, A.w, B.w};
    }
  }
  __syncthreads();

  // ---- phase 2: horizontal blur, 2 output cols per task, b128 tap reads ----
  // task (r, cp): c = 2*cp; taps for col c are pixel slots c+3..c+13,
  // for col c+1 slots c+4..c+14. Read slots c+2..c+15 as 7 b128.
  // Per-slot loop: sq/cross computed once, consumed by both columns.
  v2f hold01[3][2], hold23[3][2], hold4[3];
#pragma unroll
  for (int t = 0; t < 3; ++t) {
    int idx = t * 256 + tid;
    if (idx < NTASK) {
      int r = idx >> 4;
      int c = (idx & 15) * 2;
      const v4f* qp = (const v4f*)&s12[r][c + 2];   // 16B-aligned
      v4f q0 = qp[0], q1 = qp[1], q2 = qp[2], q3 = qp[3];
      v4f q4 = qp[4], q5 = qp[5], q6 = qp[6];
      v2f P[14];
      P[0]  = (v2f){q0.x, q0.y};  P[1]  = (v2f){q0.z, q0.w};
      P[2]  = (v2f){q1.x, q1.y};  P[3]  = (v2f){q1.z, q1.w};
      P[4]  = (v2f){q2.x, q2.y};  P[5]  = (v2f){q2.z, q2.w};
      P[6]  = (v2f){q3.x, q3.y};  P[7]  = (v2f){q3.z, q3.w};
      P[8]  = (v2f){q4.x, q4.y};  P[9]  = (v2f){q4.z, q4.w};
      P[10] = (v2f){q5.x, q5.y};  P[11] = (v2f){q5.z, q5.w};
      P[12] = (v2f){q6.x, q6.y};  P[13] = (v2f){q6.z, q6.w};

      v2f a01_0 = (v2f){0.f, 0.f}, a23_0 = (v2f){0.f, 0.f};
      v2f a01_1 = (v2f){0.f, 0.f}, a23_1 = (v2f){0.f, 0.f};
      float a4_0 = 0.f, a4_1 = 0.f;
#pragma unroll
      for (int k = 1; k <= 12; ++k) {
        v2f p = P[k];
        v2f sq = p * p;              // once per slot (was twice)
        float cr = p.x * p.y;        // once per slot (was twice)
        if (k <= 11) {               // col0 taps slots 1..11, weight g[k-1]
          float w = g[k - 1];
          a01_0 += w * p;
          a23_0 += w * sq;
          a4_0 = __builtin_fmaf(w, cr, a4_0);
        }
        if (k >= 2) {                // col1 taps slots 2..12, weight g[k-2]
          float w = g[k - 2];
          a01_1 += w * p;
          a23_1 += w * sq;
          a4_1 = __builtin_fmaf(w, cr, a4_1);
        }
      }
      hold01[t][0] = a01_0;  hold01[t][1] = a01_1;
      hold23[t][0] = a23_0;  hold23[t][1] = a23_1;
      hold4[t] = (v2f){a4_0, a4_1};
    }
  }
  __syncthreads();   // all s12 reads done; overlay H on the union

#pragma unroll
  for (int t = 0; t < 3; ++t) {
    int idx = t * 256 + tid;
    if (idx < NTASK) {
      int r = idx >> 4;
      int c = (idx & 15) * 2;
      *(v4f*)&h0123[r][c]     = (v4f){hold01[t][0].x, hold01[t][0].y,
                                      hold23[t][0].x, hold23[t][0].y};
      *(v4f*)&h0123[r][c + 1] = (v4f){hold01[t][1].x, hold01[t][1].y,
                                      hold23[t][1].x, hold23[t][1].y};
      *(v2f*)&h4[r][c] = hold4[t];
    }
  }
  __syncthreads();

  // ---- phase 3: vertical blur, 4 consecutive rows/thread, sliding window ----
  const float C1 = 1e-4f;
  const float C2 = 9e-4f;
  const int c = tid & 31;
  const int r0 = (tid >> 5) * 4;

  v2f m[4], vv[4];
  float b12[4];
#pragma unroll
  for (int o = 0; o < 4; ++o) {
    m[o] = (v2f){0.f, 0.f};
    vv[o] = (v2f){0.f, 0.f};
    b12[o] = 0.f;
  }

#pragma unroll
  for (int dy = 0; dy < 14; ++dy) {
    v4f q = h0123[r0 + dy][c];       // one b128: {mu1,mu2,sq1,sq2}
    v2f a = (v2f){q.x, q.y};
    v2f b = (v2f){q.z, q.w};
    float d = h4[r0 + dy][c];
#pragma unroll
    for (int o = 0; o < 4; ++o) {
      const int k = dy - o;
      if (k >= 0 && k < 11) {
        float w = g[k];
        m[o] += w * a;
        vv[o] += w * b;
        b12[o] = __builtin_fmaf(w, d, b12[o]);
      }
    }
  }

  float lsum = 0.f;
#pragma unroll
  for (int o = 0; o < 4; ++o) {
    float mu1 = m[o].x, mu2 = m[o].y;
    float mu1sq = mu1 * mu1;
    float mu2sq = mu2 * mu2;
    float mu12 = mu1 * mu2;
    float sig11 = vv[o].x - mu1sq;
    float sig22 = vv[o].y - mu2sq;
    float sig12 = b12[o] - mu12;
    float num = (2.f * mu12 + C1) * (2.f * sig12 + C2);
    float den = (mu1sq + mu2sq + C1) * (sig11 + sig22 + C2);
    lsum += num * __builtin_amdgcn_rcpf(den);
  }

  // wave reduction + one atomic per block into spread slots
#pragma unroll
  for (int off = 32; off > 0; off >>= 1)
    lsum += __shfl_down(lsum, off, 64);
  const int lane = tid & 63;
  const int wid = tid >> 6;
  if (lane == 0) wsum[wid] = lsum;
  __syncthreads();
  if (tid == 0) {
    float b = wsum[0] + wsum[1] + wsum[2] + wsum[3];
    int slot = (blockIdx.x + blockIdx.y * 16 + blockIdx.z) & (NACC - 1);
    atomicAdd(acc + slot, b);
  }
}

__global__ void ssim_finalize_kernel(const float* __restrict__ acc,
                                     float* __restrict__ out) {
  __shared__ float wsum[4];
  const int tid = threadIdx.x;
  float s = acc[tid];
#pragma unroll
  for (int off = 32; off > 0; off >>= 1)
    s += __shfl_down(s, off, 64);
  if ((tid & 63) == 0) wsum[tid >> 6] = s;
  __syncthreads();
  if (tid == 0)
    out[0] = 1.0f - (wsum[0] + wsum[1] + wsum[2] + wsum[3]) * (1.0f / NPIX);
}

extern "C" void kernel_launch(void* const* d_in, const int* in_sizes, int n_in,
                              void* d_out, int out_size, void* d_ws, size_t ws_size,
                              hipStream_t stream) {
  const float* img1 = (const float*)d_in[0];
  const float* img2 = (const float*)d_in[1];
  float* out = (float*)d_out;
  float* acc = (float*)d_ws;

  (void)hipMemsetAsync(acc, 0, NACC * sizeof(float), stream);

  dim3 grid(WW / TILE, HH / TILE, NPLANES);   // 16 x 16 x 96 = 24576
  ssim_fused_kernel<<<grid, 256, 0, stream>>>(img1, img2, acc);
  ssim_finalize_kernel<<<1, NACC, 0, stream>>>(acc, out);
}